// Round 1
// baseline (10.023 us; speedup 1.0000x reference)
//
#include <hip/hip_runtime.h>
#include <hip/hip_bf16.h>

#define OUT 64
#define YOFF 82
#define IMG_H 644
#define IMG_W 640

__global__ __launch_bounds__(256) void crop_resize_kernel(
    const float* __restrict__ img, const int* __restrict__ bbox,
    float* __restrict__ out)
{
    int idx = blockIdx.x * blockDim.x + threadIdx.x;  // 0 .. 64*64*64-1
    int x = idx & 63;
    int y = (idx >> 6) & 63;
    int b = idx >> 12;

    const int4 bb = ((const int4*)bbox)[b];
    int x1 = bb.x;
    int y1 = bb.y + YOFF;
    int x2 = bb.z;
    int y2 = bb.w + YOFF;
    int hi = y2 - y1;
    int wi = x2 - x1;
    float h = (float)hi;
    float w = (float)wi;

    // sy = clip((y+0.5)*h/64 - 0.5, 0, h-1); exact same fp ops as reference
    float sy = ((float)y + 0.5f) * h / 64.0f - 0.5f;
    sy = fminf(fmaxf(sy, 0.0f), h - 1.0f);
    float sx = ((float)x + 0.5f) * w / 64.0f - 0.5f;
    sx = fminf(fmaxf(sx, 0.0f), w - 1.0f);

    float y0f = floorf(sy);
    float x0f = floorf(sx);
    float wy = sy - y0f;
    float wx = sx - x0f;
    int y0 = (int)y0f;
    int x0 = (int)x0f;
    int yp = min(y0 + 1, hi - 1);
    int xp = min(x0 + 1, wi - 1);

    int gy0 = y0 + y1, gy1 = yp + y1;
    int gx0 = x0 + x1, gx1 = xp + x1;

    const float* base = img + (size_t)b * (IMG_H * IMG_W * 3);
    const float* p00 = base + ((size_t)gy0 * IMG_W + gx0) * 3;
    const float* p01 = base + ((size_t)gy0 * IMG_W + gx1) * 3;
    const float* p10 = base + ((size_t)gy1 * IMG_W + gx0) * 3;
    const float* p11 = base + ((size_t)gy1 * IMG_W + gx1) * 3;

    float omwx = 1.0f - wx;
    float omwy = 1.0f - wy;

    float* o = out + (size_t)b * 3 * (OUT * OUT) + y * OUT + x;
#pragma unroll
    for (int c = 0; c < 3; ++c) {
        float top = p00[c] * omwx + p01[c] * wx;
        float bot = p10[c] * omwx + p11[c] * wx;
        o[c * (OUT * OUT)] = top * omwy + bot * wy;
    }
}

extern "C" void kernel_launch(void* const* d_in, const int* in_sizes, int n_in,
                              void* d_out, int out_size, void* d_ws, size_t ws_size,
                              hipStream_t stream) {
    const float* img = (const float*)d_in[0];
    const int* bbox = (const int*)d_in[1];
    float* out = (float*)d_out;

    int total = 64 * OUT * OUT;  // 262144 threads
    dim3 block(256);
    dim3 grid(total / 256);
    crop_resize_kernel<<<grid, block, 0, stream>>>(img, bbox, out);
}

// Round 2
// 9.972 us; speedup vs baseline: 1.0051x; 1.0051x over previous
//
#include <hip/hip_runtime.h>
#include <hip/hip_bf16.h>

#define OUT 64
#define YOFF 82
#define IMG_H 644
#define IMG_W 640
#define ROWS 4            // output rows per block
#define RS 904            // LDS row stride in dwords (multiple of 4 for b128 writes)

__global__ __launch_bounds__(256) void crop_resize_kernel(
    const float* __restrict__ img, const int* __restrict__ bbox,
    float* __restrict__ out)
{
    __shared__ float lds[2 * ROWS * RS];   // 28.9 KB
    int tid = threadIdx.x;
    int b = blockIdx.x >> 4;               // 16 row-groups per image
    int yo_base = (blockIdx.x & 15) * ROWS;

    const int4 bb = ((const int4*)bbox)[b];
    int x1 = bb.x, y1 = bb.y + YOFF, x2 = bb.z, y2 = bb.w + YOFF;
    int hi = y2 - y1, wi = x2 - x1;
    float h = (float)hi, w = (float)wi;

    const float* base = img + (size_t)b * (IMG_H * IMG_W * 3);

    // --- staging: 2*ROWS input rows into LDS, coalesced dwordx4 ---
#pragma unroll
    for (int r8 = 0; r8 < 2 * ROWS; ++r8) {
        int r = r8 >> 1;
        int yo = yo_base + r;
        float sy = ((float)yo + 0.5f) * h / 64.0f - 0.5f;
        sy = fminf(fmaxf(sy, 0.0f), h - 1.0f);
        int y0 = (int)floorf(sy);
        int gy = ((r8 & 1) ? min(y0 + 1, hi - 1) : y0) + y1;
        int rowstart = (gy * IMG_W + x1) * 3;   // dword index
        int astart = rowstart & ~3;             // 16B-aligned floor
        int shift = rowstart & 3;
        int n_dw = wi * 3 + shift;
        int i = tid * 4;
        if (i < n_dw) {
            float4 v = *(const float4*)(base + astart + i);
            *(float4*)&lds[r8 * RS + i] = v;
        }
    }
    __syncthreads();

    // --- compute: wave r handles output row yo_base + r; lane = x ---
    int r = tid >> 6;
    int x = tid & 63;
    int yo = yo_base + r;

    float sy = ((float)yo + 0.5f) * h / 64.0f - 0.5f;
    sy = fminf(fmaxf(sy, 0.0f), h - 1.0f);
    float y0f = floorf(sy);
    float wy = sy - y0f;
    int y0i = (int)y0f;

    float sx = ((float)x + 0.5f) * w / 64.0f - 0.5f;
    sx = fminf(fmaxf(sx, 0.0f), w - 1.0f);
    float x0f = floorf(sx);
    float wx = sx - x0f;
    int x0 = (int)x0f;
    int xp = min(x0 + 1, wi - 1);

    // per-row alignment shifts (match staging)
    int gy0 = y0i + y1;
    int gy1 = min(y0i + 1, hi - 1) + y1;
    int sh0 = ((gy0 * IMG_W + x1) * 3) & 3;
    int sh1 = ((gy1 * IMG_W + x1) * 3) & 3;

    const float* r0 = &lds[(2 * r) * RS + sh0];
    const float* r1 = &lds[(2 * r + 1) * RS + sh1];

    float omwx = 1.0f - wx, omwy = 1.0f - wy;
    float* o = out + (size_t)b * 3 * (OUT * OUT) + yo * OUT + x;
#pragma unroll
    for (int c = 0; c < 3; ++c) {
        float top = r0[x0 * 3 + c] * omwx + r0[xp * 3 + c] * wx;
        float bot = r1[x0 * 3 + c] * omwx + r1[xp * 3 + c] * wx;
        o[c * (OUT * OUT)] = top * omwy + bot * wy;
    }
}

extern "C" void kernel_launch(void* const* d_in, const int* in_sizes, int n_in,
                              void* d_out, int out_size, void* d_ws, size_t ws_size,
                              hipStream_t stream) {
    const float* img = (const float*)d_in[0];
    const int* bbox = (const int*)d_in[1];
    float* out = (float*)d_out;

    dim3 block(256);
    dim3 grid(64 * (OUT / ROWS));   // 1024 blocks
    crop_resize_kernel<<<grid, block, 0, stream>>>(img, bbox, out);
}